// Round 8
// baseline (271.270 us; speedup 1.0000x reference)
//
#include <hip/hip_runtime.h>

#define NB  32
#define NC  256
#define NCQ 64
#define WHT 4096                  // 64*64 spatial
#define DQK ((size_t)NCQ * WHT)   // 262144
#define MV  ((size_t)NC * WHT)    // 1048576

typedef __attribute__((ext_vector_type(8))) short short8;
typedef __attribute__((ext_vector_type(4))) float f32x4;
typedef __attribute__((ext_vector_type(2))) float f32x2;
typedef unsigned short ushort_t;

__device__ __forceinline__ ushort_t bf16_rne(float f) {
    union { float f; unsigned u; } v; v.f = f;
    unsigned r = (v.u + 0x7fffu + ((v.u >> 16) & 1u)) >> 16;
    return (ushort_t)r;
}
__device__ __forceinline__ float bf16_f(ushort_t h) {
    union { unsigned u; float f; } v; v.u = ((unsigned)h) << 16; return v.f;
}

// fragment-order offset within one 64x256 W tile (elements):
// value W[r][kk] lands at (kb=kk>>5)*2048 + lh*512 + m*128 + ll*8 + e
__device__ __forceinline__ int frag_off(int r, int kk) {
    return ((kk >> 5) * 16 + ((kk >> 3) & 3) * 4 + (r >> 4)) * 128
           + (r & 15) * 8 + (kk & 7);
}

// async global->LDS, 16B per lane (dest = lds base + lane*16, wave-uniform base)
__device__ __forceinline__ void gload_lds16(const float* g, float* l) {
    __builtin_amdgcn_global_load_lds(
        (const __attribute__((address_space(1))) unsigned*)g,
        (__attribute__((address_space(3))) unsigned*)l, 16, 0, 0);
}

// ---------------------------------------------------------------------------
// P: convert weights to bf16 hi (+lo for q/k), permuted to MFMA fragment order
// ---------------------------------------------------------------------------
__global__ __launch_bounds__(256)
void prep_w(const float* __restrict__ Wq, const float* __restrict__ Wk,
            const float* __restrict__ Wv,
            ushort_t* __restrict__ wv_hi,
            ushort_t* __restrict__ wq_hi, ushort_t* __restrict__ wq_lo,
            ushort_t* __restrict__ wk_hi, ushort_t* __restrict__ wk_lo)
{
    int i = blockIdx.x * 256 + threadIdx.x;
    if (i < 65536) {                       // Wv: 256 rows -> 4 tiles of 64
        int R = i >> 8, kk = i & 255;
        wv_hi[(R >> 6) * 16384 + frag_off(R & 63, kk)] = bf16_rne(Wv[i]);
    } else if (i < 81920) {                // Wq: 64 rows
        int j = i - 65536; int r = j >> 8, kk = j & 255;
        float f = Wq[j]; ushort_t h = bf16_rne(f);
        int o = frag_off(r, kk);
        wq_hi[o] = h; wq_lo[o] = bf16_rne(f - bf16_f(h));
    } else if (i < 98304) {                // Wk: 64 rows
        int j = i - 81920; int r = j >> 8, kk = j & 255;
        float f = Wk[j]; ushort_t h = bf16_rne(f);
        int o = frag_off(r, kk);
        wk_hi[o] = h; wk_lo[o] = bf16_rne(f - bf16_f(h));
    }
}

// pack 8 floats -> 8 bf16 (truncate to top 16 bits) via v_perm
#define PACK_HI(dst, src) do {                                          \
    union { unsigned u[4]; short8 s; } pk_;                             \
    _Pragma("unroll") for (int p_ = 0; p_ < 4; ++p_)                    \
        pk_.u[p_] = __builtin_amdgcn_perm(                              \
            __float_as_uint(src[2 * p_ + 1]),                           \
            __float_as_uint(src[2 * p_]), 0x07060302u);                 \
    dst = pk_.s;                                                        \
} while (0)

// stage one 32ch x 256sp x-tile into LDS buffer bufi (4 channels per wave)
#define STAGE(bufi, kbv) do {                                           \
    _Pragma("unroll") for (int r_ = 0; r_ < 4; ++r_) {                  \
        const int ch_ = wave * 4 + r_;                                  \
        gload_lds16(xpanel + (size_t)((kbv) * 32 + ch_) * WHT + (lane << 2), \
                    &Xl[bufi][ch_][0]);                                 \
    }                                                                   \
} while (0)

// pull this wave's B-fragment floats for k-chunk from LDS
#define LOADXF(xf, cur) do {                                            \
    _Pragma("unroll") for (int n_ = 0; n_ < 2; ++n_)                    \
    _Pragma("unroll") for (int e_ = 0; e_ < 8; ++e_)                    \
        xf[n_][e_] = Xl[cur][lh * 8 + e_][spb + n_ * 16];               \
} while (0)

// ---------------------------------------------------------------------------
// K1: fused q/k/v projections via bf16 MFMA. 512 threads = 8 waves.
// 6 slots per (b,nt) panel: 0..3 = v 64-row tiles (x0), 4 = q (x0), 5 = k (x1),
// all on one XCD. Per-wave tile 64x32. x staged to LDS via global_load_lds
// (double-buffered 2x32KB; stage issued right after the barrier so loads fly
// during the compute phase -> nothing for the compiler to de-pipeline).
// W fragments read from global (L1/L2-resident, 16B contiguous per lane).
// q/k: 3-pass hi/lo split; v: hi-only, stored bf16.
// ---------------------------------------------------------------------------
__global__ __launch_bounds__(512, 4)
void qkv_mfma(const float* __restrict__ x0, const float* __restrict__ x1,
              const ushort_t* __restrict__ wv_hi,
              const ushort_t* __restrict__ wq_hi, const ushort_t* __restrict__ wq_lo,
              const ushort_t* __restrict__ wk_hi, const ushort_t* __restrict__ wk_lo,
              const float* __restrict__ bq, const float* __restrict__ bk,
              const float* __restrict__ bv,
              float* __restrict__ q, float* __restrict__ k,
              ushort_t* __restrict__ vbf)
{
    __shared__ float Xl[2][32][256];     // 64 KB, double-buffered x tile

    const int t   = threadIdx.x;
    const int bid = blockIdx.x;
    // bid -> (b, nt, mt): all 6 slots of one (b,nt) panel on one XCD (bid%8)
    const int xcd = bid & 7;
    const int sl  = bid >> 3;            // 0..383
    const int mt  = sl % 6;
    const int g   = (sl / 6) * 8 + xcd;  // 0..511
    const int nt  = g & 15;
    const int b   = g >> 4;

    const bool isV = (mt < 4);
    const bool isQ = (mt == 4);

    const int wave = t >> 6;
    const int lane = t & 63;
    const int lh   = lane >> 4;
    const int ll   = lane & 15;

    const float* xpanel = ((mt == 5) ? x1 : x0) + (size_t)b * NC * WHT + nt * 256;
    const ushort_t* whi = isV ? (wv_hi + mt * 16384) : (isQ ? wq_hi : wk_hi);
    const ushort_t* wlo = isQ ? wq_lo : wk_lo;

    const int abase = lh * 512 + ll * 8;
    const int spb   = wave * 32 + ll;

    f32x4 acc[4][2];
#pragma unroll
    for (int m = 0; m < 4; ++m)
#pragma unroll
        for (int n = 0; n < 2; ++n) acc[m][n] = (f32x4){0.f, 0.f, 0.f, 0.f};

    STAGE(0, 0);

    if (isV) {
#pragma unroll
        for (int kb = 0; kb < 8; ++kb) {
            asm volatile("s_waitcnt vmcnt(0)" ::: "memory");
            __syncthreads();
            if (kb < 7) STAGE((kb + 1) & 1, kb + 1);
            __builtin_amdgcn_sched_barrier(0);

            const int cur = kb & 1;
            float xf[2][8];
            LOADXF(xf, cur);

            short8 bh[2];
#pragma unroll
            for (int n = 0; n < 2; ++n) PACK_HI(bh[n], xf[n]);

#pragma unroll
            for (int m = 0; m < 4; ++m) {
                short8 ah = *(const short8*)(whi + kb * 2048 + abase + m * 128);
#pragma unroll
                for (int n = 0; n < 2; ++n)
                    acc[m][n] = __builtin_amdgcn_mfma_f32_16x16x32_bf16(
                        ah, bh[n], acc[m][n], 0, 0, 0);
            }
        }

        const int colbase = nt * 256 + wave * 32;
        ushort_t* outp = vbf + ((size_t)b * NC + mt * 64) * WHT + colbase;
        const float* bias = bv + mt * 64;
#pragma unroll
        for (int m = 0; m < 4; ++m)
#pragma unroll
            for (int n = 0; n < 2; ++n)
#pragma unroll
                for (int r = 0; r < 4; ++r) {
                    const int row = m * 16 + 4 * lh + r;
                    outp[(size_t)row * WHT + n * 16 + ll] =
                        bf16_rne(acc[m][n][r] + bias[row]);
                }
    } else {
#pragma unroll
        for (int kb = 0; kb < 8; ++kb) {
            asm volatile("s_waitcnt vmcnt(0)" ::: "memory");
            __syncthreads();
            if (kb < 7) STAGE((kb + 1) & 1, kb + 1);
            __builtin_amdgcn_sched_barrier(0);

            const int cur = kb & 1;
            float xf[2][8];
            LOADXF(xf, cur);

            short8 bh[2], bl[2];
#pragma unroll
            for (int n = 0; n < 2; ++n) {
                PACK_HI(bh[n], xf[n]);
                float lo[8];
#pragma unroll
                for (int e = 0; e < 8; ++e) {
                    float hf = __uint_as_float(__float_as_uint(xf[n][e]) & 0xffff0000u);
                    lo[e] = xf[n][e] - hf;
                }
                PACK_HI(bl[n], lo);
            }

#pragma unroll
            for (int m = 0; m < 4; ++m) {
                short8 ah = *(const short8*)(whi + kb * 2048 + abase + m * 128);
                short8 al = *(const short8*)(wlo + kb * 2048 + abase + m * 128);
#pragma unroll
                for (int n = 0; n < 2; ++n) {
                    acc[m][n] = __builtin_amdgcn_mfma_f32_16x16x32_bf16(
                        ah, bh[n], acc[m][n], 0, 0, 0);
                    acc[m][n] = __builtin_amdgcn_mfma_f32_16x16x32_bf16(
                        ah, bl[n], acc[m][n], 0, 0, 0);
                    acc[m][n] = __builtin_amdgcn_mfma_f32_16x16x32_bf16(
                        al, bh[n], acc[m][n], 0, 0, 0);
                }
            }
        }

        const int colbase = nt * 256 + wave * 32;
        float* outp = (isQ ? q : k) + (size_t)b * NCQ * WHT + colbase;
        const float* bias = isQ ? bq : bk;
#pragma unroll
        for (int m = 0; m < 4; ++m)
#pragma unroll
            for (int n = 0; n < 2; ++n)
#pragma unroll
                for (int r = 0; r < 4; ++r) {
                    const int row = m * 16 + 4 * lh + r;
                    outp[(size_t)row * WHT + n * 16 + ll] =
                        acc[m][n][r] + bias[row];
                }
    }
}

// ---------------------------------------------------------------------------
// K2: energy[i,j] = sum_d k[i,d]*q[j,d]  (32x32, K=262144)
// ---------------------------------------------------------------------------
__global__ __launch_bounds__(256)
void energy_kernel(const float* __restrict__ q, const float* __restrict__ k,
                   float* __restrict__ energy)
{
    __shared__ float kt[256][17];
    __shared__ float qt[256][17];

    const int t  = threadIdx.x;
    const int d0 = blockIdx.x * 256;
    const int ih = blockIdx.y;
    const int jh = blockIdx.z;

    for (int r = 0; r < 16; ++r) {
        kt[t][r] = k[(size_t)(ih * 16 + r) * DQK + d0 + t];
        qt[t][r] = q[(size_t)(jh * 16 + r) * DQK + d0 + t];
    }
    __syncthreads();

    const int ii = t >> 4;
    const int jj = t & 15;
    float a0 = 0.f, a1 = 0.f, a2 = 0.f, a3 = 0.f;
#pragma unroll 8
    for (int d = 0; d < 256; d += 4) {
        a0 = fmaf(kt[d + 0][ii], qt[d + 0][jj], a0);
        a1 = fmaf(kt[d + 1][ii], qt[d + 1][jj], a1);
        a2 = fmaf(kt[d + 2][ii], qt[d + 2][jj], a2);
        a3 = fmaf(kt[d + 3][ii], qt[d + 3][jj], a3);
    }

    atomicAdd(&energy[(ih * 16 + ii) * 32 + jh * 16 + jj], (a0 + a1) + (a2 + a3));
}

// ---------------------------------------------------------------------------
// K3: softmax (per-block recompute, 32x32) + out = gamma*(A@v) + x1.
// Block 0 also writes the attention output. v is bf16-packed.
// ---------------------------------------------------------------------------
__global__ __launch_bounds__(256)
void out_kernel(const ushort_t* __restrict__ vbf, const float* __restrict__ energy,
                const float* __restrict__ x1, const float* __restrict__ gamma,
                float* __restrict__ out, float* __restrict__ att_out)
{
    __shared__ float att_s[1024];
    const int t = threadIdx.x;

    if (t < 32) {
        float e[32];
        float m = -1e30f;
#pragma unroll
        for (int j = 0; j < 32; ++j) { e[j] = energy[t * 32 + j]; m = fmaxf(m, e[j]); }
        float s = 0.f;
#pragma unroll
        for (int j = 0; j < 32; ++j) { e[j] = __expf(e[j] - m); s += e[j]; }
        float inv = 1.f / s;
#pragma unroll
        for (int j = 0; j < 32; ++j) att_s[t * 32 + j] = e[j] * inv;
    }
    __syncthreads();

    if (blockIdx.x == 0) {
        for (int r = t; r < 1024; r += 256) att_out[r] = att_s[r];
    }

    const size_t m0 = (size_t)blockIdx.x * 512 + 2 * t;

    float v0[32], v1[32];
#pragma unroll
    for (int j = 0; j < 32; ++j) {
        unsigned u = *(const unsigned*)(vbf + (size_t)j * MV + m0);
        v0[j] = __uint_as_float(u << 16);
        v1[j] = __uint_as_float(u & 0xffff0000u);
    }

    const float g = gamma[0];
    for (int i = 0; i < 32; ++i) {
        float a0 = 0.f, a1 = 0.f;
#pragma unroll
        for (int j = 0; j < 32; ++j) {
            float w = att_s[i * 32 + j];
            a0 = fmaf(w, v0[j], a0);
            a1 = fmaf(w, v1[j], a1);
        }
        f32x2 xx = *(const f32x2*)(x1 + (size_t)i * MV + m0);
        f32x2 oo; oo.x = g * a0 + xx.x; oo.y = g * a1 + xx.y;
        *(f32x2*)(out + (size_t)i * MV + m0) = oo;
    }
}

// ---------------------------------------------------------------------------
extern "C" void kernel_launch(void* const* d_in, const int* in_sizes, int n_in,
                              void* d_out, int out_size, void* d_ws, size_t ws_size,
                              hipStream_t stream)
{
    const float* x0    = (const float*)d_in[0];
    const float* x1    = (const float*)d_in[1];
    const float* Wq    = (const float*)d_in[2];
    const float* bq    = (const float*)d_in[3];
    const float* Wk    = (const float*)d_in[4];
    const float* bk    = (const float*)d_in[5];
    const float* Wv    = (const float*)d_in[6];
    const float* bv    = (const float*)d_in[7];
    const float* gamma = (const float*)d_in[8];

    float* ws     = (float*)d_ws;
    float* q      = ws;                                  // 8,388,608 f
    float* k      = q + (size_t)NB * NCQ * WHT;          // 8,388,608 f
    float* energy = k + (size_t)NB * NCQ * WHT;          //     1,024 f

    ushort_t* wv_hi = (ushort_t*)(energy + 1024);        // 65,536 us (16B-aligned)
    ushort_t* wq_hi = wv_hi + 65536;
    ushort_t* wq_lo = wq_hi + 16384;
    ushort_t* wk_hi = wq_lo + 16384;
    ushort_t* wk_lo = wk_hi + 16384;
    ushort_t* vbf   = wk_lo + 16384;                     // 33,554,432 us

    float* out     = (float*)d_out;
    float* att_out = out + (size_t)NB * NC * WHT;

    hipMemsetAsync(energy, 0, 1024 * sizeof(float), stream);

    prep_w<<<384, 256, 0, stream>>>(Wq, Wk, Wv, wv_hi, wq_hi, wq_lo, wk_hi, wk_lo);
    qkv_mfma<<<3072, 512, 0, stream>>>(x0, x1, wv_hi, wq_hi, wq_lo, wk_hi, wk_lo,
                                       bq, bk, bv, q, k, vbf);
    energy_kernel<<<dim3(1024, 2, 2), 256, 0, stream>>>(q, k, energy);
    out_kernel<<<2048, 256, 0, stream>>>(vbf, energy, x1, gamma, out, att_out);
}